// Round 5
// baseline (5549.950 us; speedup 1.0000x reference)
//
#include <hip/hip_runtime.h>
#include <hip/hip_fp16.h>

#define R       8192
#define C1      8213
#define C2      8192
#define CPB     8224      // K row stride in BYTES (fp8 elems); multiple of 16
#define CPF     8224      // part/v row length in floats
#define NCH     514       // 16-byte chunks per K row (CPB/16)
#define NSPLIT  256       // row splits for column pass
#define RPS     32        // rows per split (R / NSPLIT)

typedef float f32x2 __attribute__((ext_vector_type(2)));

__device__ __forceinline__ void fp8x16_to_f(const int4 w, float f[16]) {
    f32x2 p;
    p = __builtin_amdgcn_cvt_pk_f32_fp8(w.x, false); f[0]  = p.x; f[1]  = p.y;
    p = __builtin_amdgcn_cvt_pk_f32_fp8(w.x, true);  f[2]  = p.x; f[3]  = p.y;
    p = __builtin_amdgcn_cvt_pk_f32_fp8(w.y, false); f[4]  = p.x; f[5]  = p.y;
    p = __builtin_amdgcn_cvt_pk_f32_fp8(w.y, true);  f[6]  = p.x; f[7]  = p.y;
    p = __builtin_amdgcn_cvt_pk_f32_fp8(w.z, false); f[8]  = p.x; f[9]  = p.y;
    p = __builtin_amdgcn_cvt_pk_f32_fp8(w.z, true);  f[10] = p.x; f[11] = p.y;
    p = __builtin_amdgcn_cvt_pk_f32_fp8(w.w, false); f[12] = p.x; f[13] = p.y;
    p = __builtin_amdgcn_cvt_pk_f32_fp8(w.w, true);  f[14] = p.x; f[15] = p.y;
}

__device__ __forceinline__ float fp8_to_f(int byte) {
    f32x2 p = __builtin_amdgcn_cvt_pk_f32_fp8(byte & 0xff, false);
    return p.x;
}

__device__ __forceinline__ float gm_label(float sc, int lab) {
    if (lab == 0) return fmaxf(-0.02f - sc, 0.0f) + fmaxf(sc, 0.0f);
    if (lab == 3) return fmaxf(0.09f + sc, 0.0f);
    return fmaxf(0.05f + sc, 0.0f) + fmaxf(-0.09f - sc, 0.0f); // labels 1|2
}

__device__ __forceinline__ float kval(float gm) {
    // K = exp(-M/REG), M = exp(-GM), REG = -0.2  ->  exp(5*exp(-GM)); hw exp
    return __expf(5.0f * __expf(-gm));
}

// ---- build kernels: 4 elems/thread, packed fp8 dword stores; rows zero-padded ----

__global__ __launch_bounds__(256) void build_k1(const float* __restrict__ dist,
                                                const int* __restrict__ lab,
                                                unsigned char* __restrict__ K) {
    int row = blockIdx.y;
    int j0 = (blockIdx.x * 256 + threadIdx.x) * 4;
    if (j0 >= CPB) return;
    size_t ib = (size_t)row * C1;
    float d0 = dist[ib];
    float val[4];
#pragma unroll
    for (int k = 0; k < 4; ++k) {
        int j = j0 + k;
        val[k] = 0.0f;
        if (j < C1) {
            float g = gm_label(dist[ib + j] - d0, lab[ib + j]);
            val[k] = kval(g);
        }
    }
    int p = 0;
    p = __builtin_amdgcn_cvt_pk_fp8_f32(val[0], val[1], p, false);
    p = __builtin_amdgcn_cvt_pk_fp8_f32(val[2], val[3], p, true);
    *reinterpret_cast<int*>(K + (size_t)row * CPB + j0) = p;
}

__global__ __launch_bounds__(256) void diag_k(const float* __restrict__ dist,
                                              float* __restrict__ dcol) {
    int j = blockIdx.x * 256 + threadIdx.x;
    if (j < R) dcol[j] = dist[(size_t)j * C1 + 21 + j];
}

__global__ __launch_bounds__(256) void build_k2(const float* __restrict__ dist,
                                                const float* __restrict__ dcol,
                                                unsigned char* __restrict__ K) {
    int row = blockIdx.y;
    int j0 = (blockIdx.x * 256 + threadIdx.x) * 4;
    if (j0 >= CPB) return;
    size_t ib = (size_t)row * C1 + 21;
    float val[4];
#pragma unroll
    for (int k = 0; k < 4; ++k) {
        int j = j0 + k;
        val[k] = 0.0f;
        if (j < C2) {
            float s = dist[ib + j] - dcol[j];
            float g = (j == row) ? 0.0f : fmaxf(0.09f + s, 0.0f);
            val[k] = kval(g);
        }
    }
    int p = 0;
    p = __builtin_amdgcn_cvt_pk_fp8_f32(val[0], val[1], p, false);
    p = __builtin_amdgcn_cvt_pk_fp8_f32(val[2], val[3], p, true);
    *reinterpret_cast<int*>(K + (size_t)row * CPB + j0) = p;
}

__global__ __launch_bounds__(256) void fill_f(float* __restrict__ p, int n, float val) {
    int i = blockIdx.x * 256 + threadIdx.x;
    if (i < n) p[i] = val;
}

// ---- column pass: part[s][j] = sum_{r in split s} K[r][j] * u[r]
//      grid (2 strips, 256 splits); thread owns one 16-byte chunk (16 cols), 32 rows;
//      strip-0 threads 0,1 additionally own tail chunks 512,513 ----
__global__ __launch_bounds__(256) void col_partial(const unsigned char* __restrict__ K,
                                                   const float* __restrict__ u,
                                                   float* __restrict__ part) {
    __shared__ float us[RPS];
    int tx = threadIdx.x;
    int sp = blockIdx.y;
    int r0 = sp * RPS;
    if (tx < RPS) us[tx] = u[r0 + tx];
    __syncthreads();
    int c = blockIdx.x * 256 + tx;
    bool tail = (blockIdx.x == 0) && (tx < 2);
    float acc[16], acct[16];
#pragma unroll
    for (int k = 0; k < 16; ++k) { acc[k] = 0.0f; acct[k] = 0.0f; }
    const int4* Kb = reinterpret_cast<const int4*>(K + (size_t)r0 * CPB);
    const int4* Kp = Kb + c;
    const int4* Kt = Kb + (512 + tx);
    for (int r = 0; r < RPS; ++r) {
        float uu = us[r];
        float f[16];
        fp8x16_to_f(Kp[(size_t)r * NCH], f);
#pragma unroll
        for (int k = 0; k < 16; ++k) acc[k] = fmaf(f[k], uu, acc[k]);
        if (tail) {
            float g[16];
            fp8x16_to_f(Kt[(size_t)r * NCH], g);
#pragma unroll
            for (int k = 0; k < 16; ++k) acct[k] = fmaf(g[k], uu, acct[k]);
        }
    }
    float4* prow = reinterpret_cast<float4*>(part + (size_t)sp * CPF);
#pragma unroll
    for (int q = 0; q < 4; ++q)
        prow[c * 4 + q] = make_float4(acc[q * 4], acc[q * 4 + 1], acc[q * 4 + 2], acc[q * 4 + 3]);
    if (tail) {
#pragma unroll
        for (int q = 0; q < 4; ++q)
            prow[(512 + tx) * 4 + q] =
                make_float4(acct[q * 4], acct[q * 4 + 1], acct[q * 4 + 2], acct[q * 4 + 3]);
    }
}

// ---- v[j] = bval / sum_s part[s][j]; 64 cols x 4 split-quarters per block ----
__global__ __launch_bounds__(256) void col_reduce(const float* __restrict__ part,
                                                  float* __restrict__ v, int C, float bval) {
    __shared__ float sb[4][64];
    int tx = threadIdx.x;
    int c = tx & 63, q = tx >> 6;
    int j = blockIdx.x * 64 + c;
    float s = 0.0f;
    if (j < CPF) {
        const float* p = part + (size_t)q * (NSPLIT / 4) * CPF + j;
        for (int k = 0; k < NSPLIT / 4; ++k) s += p[(size_t)k * CPF];
    }
    sb[q][c] = s;
    __syncthreads();
    if (tx < 64) {
        int jj = blockIdx.x * 64 + tx;
        if (jj < CPF) {
            float t = sb[0][tx] + sb[1][tx] + sb[2][tx] + sb[3][tx];
            v[jj] = (jj < C) ? bval / t : 0.0f;
        }
    }
}

// ---- row pass: u[i] = aval / sum_j K[i][j]*v[j]
//      no LDS; v read from global (L1-resident, 33 KB); wave owns 4 rows, no barriers ----
__global__ __launch_bounds__(256) void row_pass(const unsigned char* __restrict__ K,
                                                const float* __restrict__ v,
                                                float* __restrict__ u, float aval) {
    int tx = threadIdx.x;
    int lane = tx & 63, wv = tx >> 6;
    int rowbase = blockIdx.x * 16 + wv * 4;
    const float4* v4 = reinterpret_cast<const float4*>(v);
#pragma unroll
    for (int rr = 0; rr < 4; ++rr) {
        int row = rowbase + rr;
        const int4* K16 = reinterpret_cast<const int4*>(K + (size_t)row * CPB);
        float dot = 0.0f;
#pragma unroll
        for (int s = 0; s < 8; ++s) {
            int ch = s * 64 + lane;
            float f[16];
            fp8x16_to_f(K16[ch], f);
#pragma unroll
            for (int q = 0; q < 4; ++q) {
                float4 w = v4[ch * 4 + q];
                dot = fmaf(f[q * 4 + 0], w.x, dot);
                dot = fmaf(f[q * 4 + 1], w.y, dot);
                dot = fmaf(f[q * 4 + 2], w.z, dot);
                dot = fmaf(f[q * 4 + 3], w.w, dot);
            }
        }
        if (lane < 2) {
            int ch = 512 + lane;
            float f[16];
            fp8x16_to_f(K16[ch], f);
#pragma unroll
            for (int q = 0; q < 4; ++q) {
                float4 w = v4[ch * 4 + q];
                dot = fmaf(f[q * 4 + 0], w.x, dot);
                dot = fmaf(f[q * 4 + 1], w.y, dot);
                dot = fmaf(f[q * 4 + 2], w.z, dot);
                dot = fmaf(f[q * 4 + 3], w.w, dot);
            }
        }
#pragma unroll
        for (int off = 32; off; off >>= 1) dot += __shfl_down(dot, off, 64);
        if (lane == 0) u[row] = aval / dot;
    }
}

// ---- loss reductions ----

__device__ __forceinline__ float2 block_reduce_2(float x, float y, float* sb) {
#pragma unroll
    for (int off = 32; off; off >>= 1) {
        x += __shfl_down(x, off, 64);
        y += __shfl_down(y, off, 64);
    }
    if ((threadIdx.x & 63) == 0) {
        int w = threadIdx.x >> 6;
        sb[w] = x; sb[4 + w] = y;
    }
    __syncthreads();
    float2 r;
    r.x = sb[0] + sb[1] + sb[2] + sb[3];
    r.y = sb[4] + sb[5] + sb[6] + sb[7];
    __syncthreads();
    return r;
}

__global__ __launch_bounds__(256) void loss1_k(const unsigned char* __restrict__ K,
                                               const float* __restrict__ v,
                                               const float* __restrict__ dist,
                                               const int* __restrict__ lab,
                                               float* __restrict__ ratio) {
    __shared__ float sb[8];
    int i = blockIdx.x;
    size_t ib = (size_t)i * C1;
    float d0 = dist[ib];
    const unsigned char* Kr = K + (size_t)i * CPB;
    float num = 0, den = 0;
    for (int j0 = threadIdx.x * 4; j0 < C1; j0 += 1024) {
        int p = *reinterpret_cast<const int*>(Kr + j0);
#pragma unroll
        for (int k = 0; k < 4; ++k) {
            int j = j0 + k;
            int jc = (j < C1) ? j : (C1 - 1);
            float kv = fp8_to_f(p >> (k * 8)) * v[jc];   // K pad = 0 -> kv = 0 beyond C1
            float g = gm_label(dist[ib + jc] - d0, lab[ib + jc]);
            den += kv;
            num = fmaf(g, kv, num);
        }
    }
    float2 r = block_reduce_2(num, den, sb);
    if (threadIdx.x == 0) ratio[i] = r.x / r.y;
}

__global__ __launch_bounds__(256) void loss2_k(const unsigned char* __restrict__ K,
                                               const float* __restrict__ v,
                                               const float* __restrict__ dist,
                                               const float* __restrict__ dcol,
                                               float* __restrict__ ratio) {
    __shared__ float sb[8];
    int i = blockIdx.x;
    const unsigned char* Kr = K + (size_t)i * CPB;
    const float* Dr = dist + (size_t)i * C1 + 21;
    float num = 0, den = 0;
    for (int j0 = threadIdx.x * 4; j0 < C2; j0 += 1024) {
        int p = *reinterpret_cast<const int*>(Kr + j0);
#pragma unroll
        for (int k = 0; k < 4; ++k) {
            int j = j0 + k;
            if (j == i) continue;
            float kv = fp8_to_f(p >> (k * 8)) * v[j];
            float h = fmaxf(0.09f + Dr[j] - dcol[j], 0.0f);
            den += kv;
            num = fmaf(h, kv, num);
        }
    }
    float2 r = block_reduce_2(num, den, sb);
    if (threadIdx.x == 0) ratio[i] = r.x / r.y;
}

__global__ __launch_bounds__(256) void final_k(const float* __restrict__ r1,
                                               const float* __restrict__ r2,
                                               float* __restrict__ out) {
    __shared__ float sb[8];
    float s1 = 0, s2 = 0;
    for (int i = threadIdx.x; i < R; i += 256) { s1 += r1[i]; s2 += r2[i]; }
    float2 t = block_reduce_2(s1, s2, sb);
    if (threadIdx.x == 0)
        out[0] = t.x / ((float)R * (float)C1) + t.y / ((float)R * (float)C2);
}

static void run_phase(const unsigned char* K, float* u, float* v, float* part, int C,
                      hipStream_t stream) {
    float aval = 1.0f / (float)R;
    float bval = 1.0f / (float)C;
    fill_f<<<dim3(R / 256), 256, 0, stream>>>(u, R, aval);
    int gcr = (CPF + 63) / 64;   // 129
    for (int t = 0; t < 50; ++t) {
        col_partial<<<dim3(2, NSPLIT), 256, 0, stream>>>(K, u, part);
        col_reduce<<<dim3(gcr), 256, 0, stream>>>(part, v, C, bval);
        if (t < 49)
            row_pass<<<dim3(R / 16), 256, 0, stream>>>(K, v, u, aval);
    }
}

extern "C" void kernel_launch(void* const* d_in, const int* in_sizes, int n_in,
                              void* d_out, int out_size, void* d_ws, size_t ws_size,
                              hipStream_t stream) {
    const float* dist = (const float*)d_in[0];
    const int* lab = (const int*)d_in[1];
    float* out = (float*)d_out;
    char* ws = (char*)d_ws;

    size_t need = (size_t)R * CPB                        // K (fp8)
                + (size_t)NSPLIT * CPF * sizeof(float)   // part
                + (size_t)CPF * sizeof(float)            // v
                + 4 * (size_t)R * sizeof(float);         // u, dcol, rat1, rat2
    if (ws_size < need) return;

    size_t off = 0;
    unsigned char* K = (unsigned char*)(ws + off); off += (size_t)R * CPB;
    float* part = (float*)(ws + off);  off += (size_t)NSPLIT * CPF * sizeof(float);
    float* v = (float*)(ws + off);     off += (size_t)CPF * sizeof(float);
    float* u = (float*)(ws + off);     off += (size_t)R * sizeof(float);
    float* dcol = (float*)(ws + off);  off += (size_t)R * sizeof(float);
    float* rat1 = (float*)(ws + off);  off += (size_t)R * sizeof(float);
    float* rat2 = (float*)(ws + off);  off += (size_t)R * sizeof(float);

    int gb = (CPB / 4 + 255) / 256;  // 9 blocks per row

    // ---- phase 1 ----
    build_k1<<<dim3(gb, R), 256, 0, stream>>>(dist, lab, K);
    run_phase(K, u, v, part, C1, stream);
    loss1_k<<<dim3(R), 256, 0, stream>>>(K, v, dist, lab, rat1);

    // ---- phase 2 (reuses K buffer) ----
    diag_k<<<dim3(R / 256), 256, 0, stream>>>(dist, dcol);
    build_k2<<<dim3(gb, R), 256, 0, stream>>>(dist, dcol, K);
    run_phase(K, u, v, part, C2, stream);
    loss2_k<<<dim3(R), 256, 0, stream>>>(K, v, dist, dcol, rat2);

    final_k<<<dim3(1), 256, 0, stream>>>(rat1, rat2, out);
}